// Round 3
// baseline (226.596 us; speedup 1.0000x reference)
//
#include <hip/hip_runtime.h>
#include <math.h>

#define BB   32
#define HH   56
#define WWI  56
#define CC   256
#define LL   3136      // H*W
#define SS   16
#define NCH  56        // chunks per batch (one per image row)
#define CHL  56        // chunk length (one row)
#define NSL  98        // spatial slices for reductions (32 positions each)
#define EPSV 1e-5f

// -------------------- K1: per-(b,slice) spatial partial sum/max over C ----
// grid (32,98), block 256 (4 waves). LDS combine -> 1 partial per block.
__global__ void k_ca_partial(const float* __restrict__ x,
                             float* __restrict__ psum, float* __restrict__ pmax) {
    const int b = blockIdx.x, sl = blockIdx.y;
    const int wv = threadIdx.x >> 6, l = threadIdx.x & 63;
    const float4* x4 = (const float4*)x;
    const size_t base = ((size_t)b * LL + sl * 32) * 64;
    float4 s  = make_float4(0.f, 0.f, 0.f, 0.f);
    float4 mx = make_float4(-1e30f, -1e30f, -1e30f, -1e30f);
#pragma unroll
    for (int k = 0; k < 8; k++) {
        float4 v = x4[base + (size_t)(k * 4 + wv) * 64 + l];
        s.x += v.x; s.y += v.y; s.z += v.z; s.w += v.w;
        mx.x = fmaxf(mx.x, v.x); mx.y = fmaxf(mx.y, v.y);
        mx.z = fmaxf(mx.z, v.z); mx.w = fmaxf(mx.w, v.w);
    }
    __shared__ float4 ls[4][64], lm[4][64];
    ls[wv][l] = s; lm[wv][l] = mx;
    __syncthreads();
    if (wv == 0) {
#pragma unroll
        for (int w = 1; w < 4; w++) {
            float4 a = ls[w][l], m2 = lm[w][l];
            s.x += a.x; s.y += a.y; s.z += a.z; s.w += a.w;
            mx.x = fmaxf(mx.x, m2.x); mx.y = fmaxf(mx.y, m2.y);
            mx.z = fmaxf(mx.z, m2.z); mx.w = fmaxf(mx.w, m2.w);
        }
        ((float4*)psum)[(b * NSL + sl) * 64 + l] = s;
        ((float4*)pmax)[(b * NSL + sl) * 64 + l] = mx;
    }
}

// -------------------- K2: combine partials + ChannelAttention FC ----------
__global__ void k_ca_fc(const float* __restrict__ psum, const float* __restrict__ pmax,
                        const float* __restrict__ w1, const float* __restrict__ w2,
                        float* __restrict__ gate) {
    const int b = blockIdx.x, tid = threadIdx.x;
    __shared__ float avg[CC], mxs[CC], hsum[16];
    float s = 0.f, mx = -1e30f;
    for (int k = 0; k < NSL; k++) {
        s += psum[(b * NSL + k) * CC + tid];
        mx = fmaxf(mx, pmax[(b * NSL + k) * CC + tid]);
    }
    avg[tid] = s * (1.f / 3136.f);
    mxs[tid] = mx;
    __syncthreads();
    const int r = tid >> 4, l = tid & 15;
    float pa = 0.f, pm = 0.f;
    for (int j = 0; j < 16; j++) {
        float w = w1[r * CC + l * 16 + j];
        pa += avg[l * 16 + j] * w;
        pm += mxs[l * 16 + j] * w;
    }
#pragma unroll
    for (int d = 1; d < 16; d <<= 1) { pa += __shfl_xor(pa, d); pm += __shfl_xor(pm, d); }
    if (l == 0) hsum[r] = fmaxf(pa, 0.f) + fmaxf(pm, 0.f);
    __syncthreads();
    float o = 0.f;
#pragma unroll
    for (int r2 = 0; r2 < 16; r2++) o += hsum[r2] * w2[tid * 16 + r2];
    gate[b * CC + tid] = 1.f / (1.f + __expf(-o));
}

// -------------------- K3: per-position channel mean/max of xc -------------
// grid (784, 32): batch = blockIdx.y, no integer division.
__global__ void k_pos_reduce(const float* __restrict__ x, const float* __restrict__ gate,
                             float* __restrict__ m, float* __restrict__ cmax) {
    const int wv = threadIdx.x >> 6, l = threadIdx.x & 63;
    const int b = blockIdx.y;
    const int pos = b * LL + blockIdx.x * 4 + wv;
    float4 v = ((const float4*)x)[(size_t)pos * 64 + l];
    float4 g = ((const float4*)gate)[b * 64 + l];
    v.x *= g.x; v.y *= g.y; v.z *= g.z; v.w *= g.w;
    float s  = v.x + v.y + v.z + v.w;
    float mm = fmaxf(fmaxf(v.x, v.y), fmaxf(v.z, v.w));
#pragma unroll
    for (int d = 1; d < 64; d <<= 1) {
        s += __shfl_xor(s, d);
        mm = fmaxf(mm, __shfl_xor(mm, d));
    }
    if (l == 0) { m[pos] = s * (1.f / 256.f); cmax[pos] = mm; }
}

__device__ __forceinline__ float softplusf(float z) {
    return fmaxf(z, 0.f) + log1pf(__expf(-fabsf(z)));
}
__device__ __forceinline__ float sigmoidf(float z) {
    return 1.f / (1.f + __expf(-z));
}

// -------------------- K4: fused S6 scan + LSA conv (one block per batch) --
// 896 threads = 56 chunk-groups x 16 states (14 waves).
__global__ void k_gsa(const float* __restrict__ m, const float* __restrict__ cmax,
                      const float* __restrict__ dw, const float* __restrict__ db,
                      const float* __restrict__ Bw, const float* __restrict__ Bb,
                      const float* __restrict__ Cw, const float* __restrict__ Cb,
                      const float* __restrict__ A,  const float* __restrict__ wc,
                      float* __restrict__ sy, float* __restrict__ ssg) {
    __shared__ float ml[LL];            // channel-mean image  (12.25 KB)
    __shared__ float cl[LL];            // channel-max image
    __shared__ float syl[LL];           // sigmoid(y) staging
    __shared__ float Pl[NCH][SS], Ql[NCH][SS], hl[NCH][SS];
    __shared__ float wl[98];
    const int b = blockIdx.x, tid = threadIdx.x;
    for (int i = tid; i < LL; i += 896) {
        ml[i] = m[b * LL + i];
        cl[i] = cmax[b * LL + i];
    }
    if (tid < 98) wl[tid] = wc[tid];
    __syncthreads();

    const int g = tid >> 4, s = tid & 15;     // chunk group, state index
    const float dwv = dw[0], dbv = db[0];
    const float As = A[s], Bws = Bw[s], Bbs = Bb[s];
    const float Cws = Cw[s], Cbs = Cb[s];

    // Phase A: per-chunk (P = prod a, Q = affine offset)
    float P = 1.f, Q = 0.f;
    for (int t = 0; t < CHL; t++) {
        float mv = ml[g * CHL + t];
        float delta = softplusf(mv * dwv + dbv);
        float a  = __expf(delta * As);
        float bb = delta * mv * (mv * Bws + Bbs);
        Q = a * Q + bb;
        P *= a;
    }
    Pl[g][s] = P; Ql[g][s] = Q;
    __syncthreads();

    // Phase B: serial combine of chunk prefixes (16 lanes)
    if (g == 0) {
        float h = 0.f;
        for (int ch = 0; ch < NCH; ch++) {
            hl[ch][s] = h;
            h = Pl[ch][s] * h + Ql[ch][s];
        }
    }
    __syncthreads();

    // Phase C: emit sigmoid(y) into LDS
    float h = hl[g][s];
    for (int t = 0; t < CHL; t++) {
        float mv = ml[g * CHL + t];
        float delta = softplusf(mv * dwv + dbv);
        float a  = __expf(delta * As);
        float bb = delta * mv * (mv * Bws + Bbs);
        float c  = mv * Cws + Cbs;
        h = a * h + bb;
        float p = h * c;
#pragma unroll
        for (int d = 1; d < 16; d <<= 1) p += __shfl_xor(p, d);
        if (s == 0) syl[g * CHL + t] = sigmoidf(p);
    }

    // Phase D: LSA 7x7 conv from LDS image (no dependence on Phase C output)
    for (int pos = tid; pos < LL; pos += 896) {
        const int h0 = pos / WWI, w0 = pos - h0 * WWI;
        float acc = 0.f;
#pragma unroll
        for (int kh = 0; kh < 7; kh++) {
            int hh = h0 + kh - 3;
            if ((unsigned)hh >= (unsigned)HH) continue;
            const int rb = hh * WWI;
#pragma unroll
            for (int kw = 0; kw < 7; kw++) {
                int ww = w0 + kw - 3;
                if ((unsigned)ww >= (unsigned)WWI) continue;
                acc += ml[rb + ww] * wl[(kh * 7 + kw) * 2]
                     + cl[rb + ww] * wl[(kh * 7 + kw) * 2 + 1];
            }
        }
        ssg[b * LL + pos] = sigmoidf(acc);
    }
    __syncthreads();

    // coalesced sy write-back
    for (int i = tid; i < LL; i += 896) sy[b * LL + i] = syl[i];
}

// -------------------- K5: BN partial stats per (b,slice) ------------------
__global__ void k_bnstat(const float* __restrict__ x, const float* __restrict__ gate,
                         const float* __restrict__ sy, const float* __restrict__ ssg,
                         float* __restrict__ pb) {
    const int b = blockIdx.x, sl = blockIdx.y;
    const int wv = threadIdx.x >> 6, l = threadIdx.x & 63;
    const float4* x4 = (const float4*)x;
    float4 g = ((const float4*)gate)[b * 64 + l];
    float4 s = make_float4(0.f, 0.f, 0.f, 0.f);
    float4 q = make_float4(0.f, 0.f, 0.f, 0.f);
#pragma unroll
    for (int k = 0; k < 8; k++) {
        int pos = b * LL + sl * 32 + k * 4 + wv;
        float4 v = x4[(size_t)pos * 64 + l];
        float g2 = sy[pos] + ssg[pos];
        float fx = v.x * g.x * g2, fy = v.y * g.y * g2, fz = v.z * g.z * g2, fw = v.w * g.w * g2;
        s.x += fx; s.y += fy; s.z += fz; s.w += fw;
        q.x += fx * fx; q.y += fy * fy; q.z += fz * fz; q.w += fw * fw;
    }
    __shared__ float4 ls[4][64], lq[4][64];
    ls[wv][l] = s; lq[wv][l] = q;
    __syncthreads();
    if (wv == 0) {
#pragma unroll
        for (int w = 1; w < 4; w++) {
            float4 a = ls[w][l], c = lq[w][l];
            s.x += a.x; s.y += a.y; s.z += a.z; s.w += a.w;
            q.x += c.x; q.y += c.y; q.z += c.z; q.w += c.w;
        }
        ((float4*)pb)[(b * NSL + sl) * 128 + l] = s;
        ((float4*)pb)[(b * NSL + sl) * 128 + 64 + l] = q;
    }
}

// -------------------- K6: BN reduce + finalize (one block per channel) ----
__global__ void k_bnfin(const float* __restrict__ pb,
                        const float* __restrict__ gamma, const float* __restrict__ beta,
                        float* __restrict__ sc, float* __restrict__ sh) {
    const int c = blockIdx.x;    // channel
    const int tid = threadIdx.x; // 256
    float s0 = 0.f, q0 = 0.f;
    for (int sl = tid; sl < BB * NSL; sl += 256) {
        s0 += pb[(size_t)sl * 512 + c];
        q0 += pb[(size_t)sl * 512 + 256 + c];
    }
    __shared__ float rs[256], rq[256];
    rs[tid] = s0; rq[tid] = q0;
    __syncthreads();
    for (int d = 128; d > 0; d >>= 1) {
        if (tid < d) { rs[tid] += rs[tid + d]; rq[tid] += rq[tid + d]; }
        __syncthreads();
    }
    if (tid == 0) {
        const float inv = 1.f / (float)(BB * LL);
        float mean = rs[0] * inv;
        float var  = rq[0] * inv - mean * mean;
        float sv = gamma[c] * rsqrtf(var + EPSV);
        sc[c] = sv;
        sh[c] = beta[c] - mean * sv;
    }
}

// -------------------- K7: normalize + ReLU + write ------------------------
// grid (784, 32): batch = blockIdx.y, one wave per position, no div.
__global__ void k_final(const float* __restrict__ x, const float* __restrict__ gate,
                        const float* __restrict__ sy, const float* __restrict__ ssg,
                        const float* __restrict__ sc, const float* __restrict__ sh,
                        float* __restrict__ out) {
    const int wv = threadIdx.x >> 6, l = threadIdx.x & 63;
    const int b = blockIdx.y;
    const int pos = b * LL + blockIdx.x * 4 + wv;
    const float4 scv = ((const float4*)sc)[l];
    const float4 shv = ((const float4*)sh)[l];
    float4 v = ((const float4*)x)[(size_t)pos * 64 + l];
    float4 g = ((const float4*)gate)[b * 64 + l];
    float g2 = sy[pos] + ssg[pos];
    float4 o;
    o.x = fmaxf(v.x * g.x * g2 * scv.x + shv.x, 0.f);
    o.y = fmaxf(v.y * g.y * g2 * scv.y + shv.y, 0.f);
    o.z = fmaxf(v.z * g.z * g2 * scv.z + shv.z, 0.f);
    o.w = fmaxf(v.w * g.w * g2 * scv.w + shv.w, 0.f);
    ((float4*)out)[(size_t)pos * 64 + l] = o;
}

extern "C" void kernel_launch(void* const* d_in, const int* in_sizes, int n_in,
                              void* d_out, int out_size, void* d_ws, size_t ws_size,
                              hipStream_t stream) {
    const float* x     = (const float*)d_in[0];
    const float* ca_w1 = (const float*)d_in[1];
    const float* ca_w2 = (const float*)d_in[2];
    const float* lsa_w = (const float*)d_in[3];
    const float* A     = (const float*)d_in[4];
    const float* d_wp  = (const float*)d_in[5];
    const float* d_bp  = (const float*)d_in[6];
    const float* B_wp  = (const float*)d_in[7];
    const float* B_bp  = (const float*)d_in[8];
    const float* C_wp  = (const float*)d_in[9];
    const float* C_bp  = (const float*)d_in[10];
    const float* bn_g  = (const float*)d_in[11];
    const float* bn_b  = (const float*)d_in[12];
    float* out = (float*)d_out;

    // Large partial buffers live in d_out (fully overwritten by k_final).
    float* psum = out;                         // 32*98*256
    float* pmax = psum + BB * NSL * CC;        // 32*98*256
    float* pb   = pmax + BB * NSL * CC;        // 32*98*512  (total 3.2M floats < 25.7M)

    float* ws    = (float*)d_ws;
    float* gate  = ws;                 // 8192
    float* m     = gate  + 8192;       // 100352
    float* cmax  = m     + 100352;     // 100352
    float* sy    = cmax  + 100352;     // 100352
    float* ssg   = sy    + 100352;     // 100352
    float* scv   = ssg   + 100352;     // 256
    float* shv   = scv   + 256;        // 256

    k_ca_partial<<<dim3(BB, NSL), 256, 0, stream>>>(x, psum, pmax);
    k_ca_fc<<<BB, 256, 0, stream>>>(psum, pmax, ca_w1, ca_w2, gate);
    k_pos_reduce<<<dim3(LL / 4, BB), 256, 0, stream>>>(x, gate, m, cmax);
    k_gsa<<<BB, 896, 0, stream>>>(m, cmax, d_wp, d_bp, B_wp, B_bp, C_wp, C_bp, A, lsa_w, sy, ssg);
    k_bnstat<<<dim3(BB, NSL), 256, 0, stream>>>(x, gate, sy, ssg, pb);
    k_bnfin<<<CC, 256, 0, stream>>>(pb, bn_g, bn_b, scv, shv);
    k_final<<<dim3(LL / 4, BB), 256, 0, stream>>>(x, gate, sy, ssg, scv, shv, out);
}

// Round 4
// 146.977 us; speedup vs baseline: 1.5417x; 1.5417x over previous
//
#include <hip/hip_runtime.h>
#include <math.h>

#define BB   32
#define HH   56
#define WWI  56
#define CC   256
#define LL   3136      // H*W
#define SS   16
#define NCH  56        // chunks per batch (one per image row)
#define CHL  56        // chunk length (one row)
#define NSL  98        // spatial slices for reductions (32 positions each)
#define EPSV 1e-5f

// -------------------- K1: per-(b,slice) spatial partial sum/max over C ----
// grid (32,98), block 256 (4 waves). LDS combine -> 1 partial per block.
__global__ void k_ca_partial(const float* __restrict__ x,
                             float* __restrict__ psum, float* __restrict__ pmax) {
    const int b = blockIdx.x, sl = blockIdx.y;
    const int wv = threadIdx.x >> 6, l = threadIdx.x & 63;
    const float4* x4 = (const float4*)x;
    const size_t base = ((size_t)b * LL + sl * 32) * 64;
    float4 s  = make_float4(0.f, 0.f, 0.f, 0.f);
    float4 mx = make_float4(-1e30f, -1e30f, -1e30f, -1e30f);
#pragma unroll
    for (int k = 0; k < 8; k++) {
        float4 v = x4[base + (size_t)(k * 4 + wv) * 64 + l];
        s.x += v.x; s.y += v.y; s.z += v.z; s.w += v.w;
        mx.x = fmaxf(mx.x, v.x); mx.y = fmaxf(mx.y, v.y);
        mx.z = fmaxf(mx.z, v.z); mx.w = fmaxf(mx.w, v.w);
    }
    __shared__ float4 ls[4][64], lm[4][64];
    ls[wv][l] = s; lm[wv][l] = mx;
    __syncthreads();
    if (wv == 0) {
#pragma unroll
        for (int w = 1; w < 4; w++) {
            float4 a = ls[w][l], m2 = lm[w][l];
            s.x += a.x; s.y += a.y; s.z += a.z; s.w += a.w;
            mx.x = fmaxf(mx.x, m2.x); mx.y = fmaxf(mx.y, m2.y);
            mx.z = fmaxf(mx.z, m2.z); mx.w = fmaxf(mx.w, m2.w);
        }
        ((float4*)psum)[(b * NSL + sl) * 64 + l] = s;
        ((float4*)pmax)[(b * NSL + sl) * 64 + l] = mx;
    }
}

// -------------------- K2: combine partials + ChannelAttention FC ----------
__global__ void k_ca_fc(const float* __restrict__ psum, const float* __restrict__ pmax,
                        const float* __restrict__ w1, const float* __restrict__ w2,
                        float* __restrict__ gate) {
    const int b = blockIdx.x, tid = threadIdx.x;
    __shared__ float avg[CC], mxs[CC], hsum[16];
    float s = 0.f, mx = -1e30f;
    for (int k = 0; k < NSL; k++) {
        s += psum[(b * NSL + k) * CC + tid];
        mx = fmaxf(mx, pmax[(b * NSL + k) * CC + tid]);
    }
    avg[tid] = s * (1.f / 3136.f);
    mxs[tid] = mx;
    __syncthreads();
    const int r = tid >> 4, l = tid & 15;
    float pa = 0.f, pm = 0.f;
    for (int j = 0; j < 16; j++) {
        float w = w1[r * CC + l * 16 + j];
        pa += avg[l * 16 + j] * w;
        pm += mxs[l * 16 + j] * w;
    }
#pragma unroll
    for (int d = 1; d < 16; d <<= 1) { pa += __shfl_xor(pa, d); pm += __shfl_xor(pm, d); }
    if (l == 0) hsum[r] = fmaxf(pa, 0.f) + fmaxf(pm, 0.f);
    __syncthreads();
    float o = 0.f;
#pragma unroll
    for (int r2 = 0; r2 < 16; r2++) o += hsum[r2] * w2[tid * 16 + r2];
    gate[b * CC + tid] = 1.f / (1.f + __expf(-o));
}

__device__ __forceinline__ float softplusf(float z) {
    // fast: |err| <= ~1e-7 absolute, fine vs 0.11 threshold
    return fmaxf(z, 0.f) + __logf(1.f + __expf(-fabsf(z)));
}
__device__ __forceinline__ float sigmoidf(float z) {
    return 1.f / (1.f + __expf(-z));
}

// -------------------- K3: per-position channel mean/max + delta precompute -
// grid (784, 32): batch = blockIdx.y. Writes m, cmax, and mdd = {m, delta, dm, 0}.
__global__ void k_pos_reduce(const float* __restrict__ x, const float* __restrict__ gate,
                             const float* __restrict__ dw, const float* __restrict__ db,
                             float* __restrict__ m, float* __restrict__ cmax,
                             float4* __restrict__ mdd) {
    const int wv = threadIdx.x >> 6, l = threadIdx.x & 63;
    const int b = blockIdx.y;
    const int pos = b * LL + blockIdx.x * 4 + wv;
    float4 v = ((const float4*)x)[(size_t)pos * 64 + l];
    float4 g = ((const float4*)gate)[b * 64 + l];
    v.x *= g.x; v.y *= g.y; v.z *= g.z; v.w *= g.w;
    float s  = v.x + v.y + v.z + v.w;
    float mm = fmaxf(fmaxf(v.x, v.y), fmaxf(v.z, v.w));
#pragma unroll
    for (int d = 1; d < 64; d <<= 1) {
        s += __shfl_xor(s, d);
        mm = fmaxf(mm, __shfl_xor(mm, d));
    }
    if (l == 0) {
        float mv = s * (1.f / 256.f);
        m[pos] = mv;
        cmax[pos] = mm;
        float dl = softplusf(mv * dw[0] + db[0]);
        mdd[pos] = make_float4(mv, dl, dl * mv, 0.f);
    }
}

// -------------------- K4: scan phase 1 — per-chunk (P,Q) ------------------
// grid 448, block 64: 4 groups x 16 states per block; group = (b, chunk).
__global__ void k_scan1(const float4* __restrict__ mdd,
                        const float* __restrict__ Bw, const float* __restrict__ Bb,
                        const float* __restrict__ A,
                        float* __restrict__ Pp, float* __restrict__ Qq) {
    const int tid = threadIdx.x;
    const int gg = blockIdx.x * 4 + (tid >> 4);   // global group 0..1791
    const int s = tid & 15;
    const int b = gg / NCH, ch = gg - b * NCH;
    const int base = b * LL + ch * CHL;
    const float As = A[s], Bws = Bw[s], Bbs = Bb[s];
    float sumd = 0.f, Q = 0.f;
    for (int t = 0; t < CHL; t++) {
        float4 md = mdd[base + t];                // {m, delta, dm, .}
        float a = __expf(md.y * As);
        Q = a * Q + md.z * (md.x * Bws + Bbs);
        sumd += md.y;
    }
    const int idx = ch * 512 + b * 16 + s;        // [chunk][b][s]
    Pp[idx] = __expf(sumd * As);
    Qq[idx] = Q;
}

// -------------------- K5: scan phase 2 — combine chunk prefixes -----------
__global__ void k_scan2(const float* __restrict__ Pp, const float* __restrict__ Qq,
                        float* __restrict__ hst) {
    const int tid = threadIdx.x;  // b*16+s
    float h = 0.f;
    for (int k = 0; k < NCH; k++) {
        int idx = k * 512 + tid;
        hst[idx] = h;
        h = Pp[idx] * h + Qq[idx];
    }
}

// -------------------- K6: scan phase 3 — emit sigmoid(y) ------------------
// grid 448, block 64.
__global__ void k_scan3(const float4* __restrict__ mdd, const float* __restrict__ hst,
                        const float* __restrict__ Bw, const float* __restrict__ Bb,
                        const float* __restrict__ Cw, const float* __restrict__ Cb,
                        const float* __restrict__ A,
                        float* __restrict__ sy) {
    const int tid = threadIdx.x;
    const int gg = blockIdx.x * 4 + (tid >> 4);
    const int s = tid & 15;
    const int b = gg / NCH, ch = gg - b * NCH;
    const int base = b * LL + ch * CHL;
    const float As = A[s], Bws = Bw[s], Bbs = Bb[s];
    const float Cws = Cw[s], Cbs = Cb[s];
    float h = hst[ch * 512 + b * 16 + s];
    for (int t = 0; t < CHL; t++) {
        float4 md = mdd[base + t];
        float a = __expf(md.y * As);
        h = a * h + md.z * (md.x * Bws + Bbs);
        float p = h * (md.x * Cws + Cbs);
#pragma unroll
        for (int d = 1; d < 16; d <<= 1) p += __shfl_xor(p, d);
        if (s == 0) sy[base + t] = sigmoidf(p);
    }
}

// -------------------- K7: LSA 7x7 conv + sigmoid --------------------------
__global__ void k_lsa(const float* __restrict__ m, const float* __restrict__ cmax,
                      const float* __restrict__ wc, float* __restrict__ ssg) {
    __shared__ float w[98];
    const int b = blockIdx.x, h = blockIdx.y, tid = threadIdx.x;
    for (int i = tid; i < 98; i += 64) w[i] = wc[i];
    __syncthreads();
    if (tid >= WWI) return;
    float acc = 0.f;
    for (int kh = 0; kh < 7; kh++) {
        int hh = h + kh - 3;
        if ((unsigned)hh >= (unsigned)HH) continue;
        const int rb = b * LL + hh * WWI;
        for (int kw = 0; kw < 7; kw++) {
            int ww = tid + kw - 3;
            if ((unsigned)ww >= (unsigned)WWI) continue;
            acc += m[rb + ww] * w[(kh * 7 + kw) * 2] + cmax[rb + ww] * w[(kh * 7 + kw) * 2 + 1];
        }
    }
    ssg[b * LL + h * WWI + tid] = sigmoidf(acc);
}

// -------------------- K8: BN partial stats per (b,slice) ------------------
__global__ void k_bnstat(const float* __restrict__ x, const float* __restrict__ gate,
                         const float* __restrict__ sy, const float* __restrict__ ssg,
                         float* __restrict__ pb) {
    const int b = blockIdx.x, sl = blockIdx.y;
    const int wv = threadIdx.x >> 6, l = threadIdx.x & 63;
    const float4* x4 = (const float4*)x;
    float4 g = ((const float4*)gate)[b * 64 + l];
    float4 s = make_float4(0.f, 0.f, 0.f, 0.f);
    float4 q = make_float4(0.f, 0.f, 0.f, 0.f);
#pragma unroll
    for (int k = 0; k < 8; k++) {
        int pos = b * LL + sl * 32 + k * 4 + wv;
        float4 v = x4[(size_t)pos * 64 + l];
        float g2 = sy[pos] + ssg[pos];
        float fx = v.x * g.x * g2, fy = v.y * g.y * g2, fz = v.z * g.z * g2, fw = v.w * g.w * g2;
        s.x += fx; s.y += fy; s.z += fz; s.w += fw;
        q.x += fx * fx; q.y += fy * fy; q.z += fz * fz; q.w += fw * fw;
    }
    __shared__ float4 ls[4][64], lq[4][64];
    ls[wv][l] = s; lq[wv][l] = q;
    __syncthreads();
    if (wv == 0) {
#pragma unroll
        for (int w = 1; w < 4; w++) {
            float4 a = ls[w][l], c = lq[w][l];
            s.x += a.x; s.y += a.y; s.z += a.z; s.w += a.w;
            q.x += c.x; q.y += c.y; q.z += c.z; q.w += c.w;
        }
        ((float4*)pb)[(b * NSL + sl) * 128 + l] = s;
        ((float4*)pb)[(b * NSL + sl) * 128 + 64 + l] = q;
    }
}

// -------------------- K9: BN reduce + finalize (one block per channel) ----
__global__ void k_bnfin(const float* __restrict__ pb,
                        const float* __restrict__ gamma, const float* __restrict__ beta,
                        float* __restrict__ sc, float* __restrict__ sh) {
    const int c = blockIdx.x;
    const int tid = threadIdx.x;
    float s0 = 0.f, q0 = 0.f;
    for (int sl = tid; sl < BB * NSL; sl += 256) {
        s0 += pb[(size_t)sl * 512 + c];
        q0 += pb[(size_t)sl * 512 + 256 + c];
    }
    __shared__ float rs[256], rq[256];
    rs[tid] = s0; rq[tid] = q0;
    __syncthreads();
    for (int d = 128; d > 0; d >>= 1) {
        if (tid < d) { rs[tid] += rs[tid + d]; rq[tid] += rq[tid + d]; }
        __syncthreads();
    }
    if (tid == 0) {
        const float inv = 1.f / (float)(BB * LL);
        float mean = rs[0] * inv;
        float var  = rq[0] * inv - mean * mean;
        float sv = gamma[c] * rsqrtf(var + EPSV);
        sc[c] = sv;
        sh[c] = beta[c] - mean * sv;
    }
}

// -------------------- K10: normalize + ReLU + write -----------------------
__global__ void k_final(const float* __restrict__ x, const float* __restrict__ gate,
                        const float* __restrict__ sy, const float* __restrict__ ssg,
                        const float* __restrict__ sc, const float* __restrict__ sh,
                        float* __restrict__ out) {
    const int wv = threadIdx.x >> 6, l = threadIdx.x & 63;
    const int b = blockIdx.y;
    const int pos = b * LL + blockIdx.x * 4 + wv;
    const float4 scv = ((const float4*)sc)[l];
    const float4 shv = ((const float4*)sh)[l];
    float4 v = ((const float4*)x)[(size_t)pos * 64 + l];
    float4 g = ((const float4*)gate)[b * 64 + l];
    float g2 = sy[pos] + ssg[pos];
    float4 o;
    o.x = fmaxf(v.x * g.x * g2 * scv.x + shv.x, 0.f);
    o.y = fmaxf(v.y * g.y * g2 * scv.y + shv.y, 0.f);
    o.z = fmaxf(v.z * g.z * g2 * scv.z + shv.z, 0.f);
    o.w = fmaxf(v.w * g.w * g2 * scv.w + shv.w, 0.f);
    ((float4*)out)[(size_t)pos * 64 + l] = o;
}

extern "C" void kernel_launch(void* const* d_in, const int* in_sizes, int n_in,
                              void* d_out, int out_size, void* d_ws, size_t ws_size,
                              hipStream_t stream) {
    const float* x     = (const float*)d_in[0];
    const float* ca_w1 = (const float*)d_in[1];
    const float* ca_w2 = (const float*)d_in[2];
    const float* lsa_w = (const float*)d_in[3];
    const float* A     = (const float*)d_in[4];
    const float* d_wp  = (const float*)d_in[5];
    const float* d_bp  = (const float*)d_in[6];
    const float* B_wp  = (const float*)d_in[7];
    const float* B_bp  = (const float*)d_in[8];
    const float* C_wp  = (const float*)d_in[9];
    const float* C_bp  = (const float*)d_in[10];
    const float* bn_g  = (const float*)d_in[11];
    const float* bn_b  = (const float*)d_in[12];
    float* out = (float*)d_out;

    // Large partial buffers live in d_out (fully overwritten by k_final).
    float* psum = out;                         // 32*98*256
    float* pmax = psum + BB * NSL * CC;        // 32*98*256
    float* pb   = pmax + BB * NSL * CC;        // 32*98*512  (total 3.2M floats < 25.7M)

    float* ws    = (float*)d_ws;
    float* gate  = ws;                 // 8192
    float* m     = gate  + 8192;       // 100352
    float* cmax  = m     + 100352;     // 100352
    float* sy    = cmax  + 100352;     // 100352
    float* ssg   = sy    + 100352;     // 100352
    float4* mdd  = (float4*)(ssg + 100352);   // 100352 float4s (16B-aligned: offset 409600 floats)
    float* Pp    = (float*)(mdd + 100352);    // 28672
    float* Qq    = Pp    + 28672;      // 28672
    float* hst   = Qq    + 28672;      // 28672
    float* scv   = hst   + 28672;      // 256
    float* shv   = scv   + 256;        // 256

    k_ca_partial<<<dim3(BB, NSL), 256, 0, stream>>>(x, psum, pmax);
    k_ca_fc<<<BB, 256, 0, stream>>>(psum, pmax, ca_w1, ca_w2, gate);
    k_pos_reduce<<<dim3(LL / 4, BB), 256, 0, stream>>>(x, gate, d_wp, d_bp, m, cmax, mdd);
    k_scan1<<<448, 64, 0, stream>>>(mdd, B_wp, B_bp, A, Pp, Qq);
    k_scan2<<<1, 512, 0, stream>>>(Pp, Qq, hst);
    k_scan3<<<448, 64, 0, stream>>>(mdd, hst, B_wp, B_bp, C_wp, C_bp, A, sy);
    k_lsa<<<dim3(BB, HH), 64, 0, stream>>>(m, cmax, lsa_w, ssg);
    k_bnstat<<<dim3(BB, NSL), 256, 0, stream>>>(x, gate, sy, ssg, pb);
    k_bnfin<<<CC, 256, 0, stream>>>(pb, bn_g, bn_b, scv, shv);
    k_final<<<dim3(LL / 4, BB), 256, 0, stream>>>(x, gate, sy, ssg, scv, shv, out);
}

// Round 5
// 131.275 us; speedup vs baseline: 1.7261x; 1.1196x over previous
//
#include <hip/hip_runtime.h>
#include <math.h>

#define BB   32
#define HH   56
#define WWI  56
#define CC   256
#define LL   3136      // H*W
#define SS   16
#define NCH  56        // chunks per batch (one per image row)
#define CHL  56        // chunk length (one row)
#define NSL  98        // spatial slices for reductions (32 positions each)
#define EPSV 1e-5f

// -------------------- K1: per-(b,slice) spatial partial sum/max over C ----
// grid (32,98), block 256 (4 waves). LDS combine -> 1 partial per block.
__global__ void k_ca_partial(const float* __restrict__ x,
                             float* __restrict__ psum, float* __restrict__ pmax) {
    const int b = blockIdx.x, sl = blockIdx.y;
    const int wv = threadIdx.x >> 6, l = threadIdx.x & 63;
    const float4* x4 = (const float4*)x;
    const size_t base = ((size_t)b * LL + sl * 32) * 64;
    float4 s  = make_float4(0.f, 0.f, 0.f, 0.f);
    float4 mx = make_float4(-1e30f, -1e30f, -1e30f, -1e30f);
#pragma unroll
    for (int k = 0; k < 8; k++) {
        float4 v = x4[base + (size_t)(k * 4 + wv) * 64 + l];
        s.x += v.x; s.y += v.y; s.z += v.z; s.w += v.w;
        mx.x = fmaxf(mx.x, v.x); mx.y = fmaxf(mx.y, v.y);
        mx.z = fmaxf(mx.z, v.z); mx.w = fmaxf(mx.w, v.w);
    }
    __shared__ float4 ls[4][64], lm[4][64];
    ls[wv][l] = s; lm[wv][l] = mx;
    __syncthreads();
    if (wv == 0) {
#pragma unroll
        for (int w = 1; w < 4; w++) {
            float4 a = ls[w][l], m2 = lm[w][l];
            s.x += a.x; s.y += a.y; s.z += a.z; s.w += a.w;
            mx.x = fmaxf(mx.x, m2.x); mx.y = fmaxf(mx.y, m2.y);
            mx.z = fmaxf(mx.z, m2.z); mx.w = fmaxf(mx.w, m2.w);
        }
        ((float4*)psum)[(b * NSL + sl) * 64 + l] = s;
        ((float4*)pmax)[(b * NSL + sl) * 64 + l] = mx;
    }
}

// -------------------- K2: combine partials + ChannelAttention FC ----------
__global__ void k_ca_fc(const float* __restrict__ psum, const float* __restrict__ pmax,
                        const float* __restrict__ w1, const float* __restrict__ w2,
                        float* __restrict__ gate) {
    const int b = blockIdx.x, tid = threadIdx.x;
    __shared__ float avg[CC], mxs[CC], hsum[16];
    float s = 0.f, mx = -1e30f;
    for (int k = 0; k < NSL; k++) {
        s += psum[(b * NSL + k) * CC + tid];
        mx = fmaxf(mx, pmax[(b * NSL + k) * CC + tid]);
    }
    avg[tid] = s * (1.f / 3136.f);
    mxs[tid] = mx;
    __syncthreads();
    const int r = tid >> 4, l = tid & 15;
    float pa = 0.f, pm = 0.f;
    for (int j = 0; j < 16; j++) {
        float w = w1[r * CC + l * 16 + j];
        pa += avg[l * 16 + j] * w;
        pm += mxs[l * 16 + j] * w;
    }
#pragma unroll
    for (int d = 1; d < 16; d <<= 1) { pa += __shfl_xor(pa, d); pm += __shfl_xor(pm, d); }
    if (l == 0) hsum[r] = fmaxf(pa, 0.f) + fmaxf(pm, 0.f);
    __syncthreads();
    float o = 0.f;
#pragma unroll
    for (int r2 = 0; r2 < 16; r2++) o += hsum[r2] * w2[tid * 16 + r2];
    gate[b * CC + tid] = 1.f / (1.f + __expf(-o));
}

__device__ __forceinline__ float softplusf(float z) {
    return fmaxf(z, 0.f) + __logf(1.f + __expf(-fabsf(z)));
}
__device__ __forceinline__ float sigmoidf(float z) {
    return 1.f / (1.f + __expf(-z));
}

// -------------------- K3: per-position channel mean/max + delta precompute -
// grid (196, 32): each wave handles 4 positions.
__global__ void k_pos_reduce(const float* __restrict__ x, const float* __restrict__ gate,
                             const float* __restrict__ dw, const float* __restrict__ db,
                             float* __restrict__ m, float* __restrict__ cmax,
                             float4* __restrict__ mdd) {
    const int wv = threadIdx.x >> 6, l = threadIdx.x & 63;
    const int b = blockIdx.y;
    float4 g = ((const float4*)gate)[b * 64 + l];
    const float dwv = dw[0], dbv = db[0];
#pragma unroll
    for (int k = 0; k < 4; k++) {
        const int pos = b * LL + blockIdx.x * 16 + k * 4 + wv;
        float4 v = ((const float4*)x)[(size_t)pos * 64 + l];
        v.x *= g.x; v.y *= g.y; v.z *= g.z; v.w *= g.w;
        float s  = v.x + v.y + v.z + v.w;
        float mm = fmaxf(fmaxf(v.x, v.y), fmaxf(v.z, v.w));
#pragma unroll
        for (int d = 1; d < 64; d <<= 1) {
            s += __shfl_xor(s, d);
            mm = fmaxf(mm, __shfl_xor(mm, d));
        }
        if (l == 0) {
            float mv = s * (1.f / 256.f);
            m[pos] = mv;
            cmax[pos] = mm;
            float dl = softplusf(mv * dwv + dbv);
            mdd[pos] = make_float4(mv, dl, dl * mv, 0.f);
        }
    }
}

// -------------------- K4: fused S6 scan (blocks 0..31) + LSA (blocks 32..63)
// 896 threads. Scan: 56 chunk-groups x 16 states, mdd staged in LDS.
__global__ void k_gsa2(const float4* __restrict__ mdd,
                       const float* __restrict__ m, const float* __restrict__ cmax,
                       const float* __restrict__ Bw, const float* __restrict__ Bb,
                       const float* __restrict__ Cw, const float* __restrict__ Cb,
                       const float* __restrict__ A,  const float* __restrict__ wc,
                       float* __restrict__ sy, float* __restrict__ ssg) {
    __shared__ __align__(16) char smem[60928];
    const int tid = threadIdx.x;

    if (blockIdx.x < BB) {
        // ---------------- scan branch ----------------
        const int b = blockIdx.x;
        float4* mddl = (float4*)smem;                      // [3136] 50176 B
        float*  Pl   = (float*)(smem + 50176);             // [56*16] 3584 B
        float*  Ql   = (float*)(smem + 50176 + 3584);      // [56*16]
        float*  hl   = (float*)(smem + 50176 + 7168);      // [56*16]
        for (int i = tid; i < LL; i += 896) mddl[i] = mdd[b * LL + i];
        __syncthreads();

        const int g = tid >> 4, s = tid & 15;              // chunk, state
        const float As = A[s], Bws = Bw[s], Bbs = Bb[s];
        const float Cws = Cw[s], Cbs = Cb[s];

        // Phase A: per-chunk (P = exp(As*sum delta), Q)
        float sumd = 0.f, Q = 0.f;
        for (int t = 0; t < CHL; t++) {
            float4 md = mddl[g * CHL + t];                 // {m, delta, dm, .}
            float a = __expf(md.y * As);
            Q = a * Q + md.z * (md.x * Bws + Bbs);
            sumd += md.y;
        }
        Pl[g * 16 + s] = __expf(sumd * As);
        Ql[g * 16 + s] = Q;
        __syncthreads();

        // Phase B: serial combine over chunks (16 lanes) from LDS
        if (g == 0) {
            float h = 0.f;
            for (int ch = 0; ch < NCH; ch++) {
                hl[ch * 16 + s] = h;
                h = Pl[ch * 16 + s] * h + Ql[ch * 16 + s];
            }
        }
        __syncthreads();

        // Phase C: emit sigmoid(y)
        float h = hl[g * 16 + s];
        for (int t = 0; t < CHL; t++) {
            float4 md = mddl[g * CHL + t];
            float a = __expf(md.y * As);
            h = a * h + md.z * (md.x * Bws + Bbs);
            float p = h * (md.x * Cws + Cbs);
#pragma unroll
            for (int d = 1; d < 16; d <<= 1) p += __shfl_xor(p, d);
            if (s == 0) sy[b * LL + g * CHL + t] = sigmoidf(p);
        }
    } else {
        // ---------------- LSA branch ----------------
        const int b = blockIdx.x - BB;
        float* ml = (float*)smem;                          // [3136]
        float* cl = (float*)(smem + 12544);                // [3136]
        float* wl = (float*)(smem + 25088);                // [98]
        for (int i = tid; i < LL; i += 896) {
            ml[i] = m[b * LL + i];
            cl[i] = cmax[b * LL + i];
        }
        if (tid < 98) wl[tid] = wc[tid];
        __syncthreads();
        for (int pos = tid; pos < LL; pos += 896) {
            const int h0 = pos / WWI, w0 = pos - h0 * WWI;
            float acc = 0.f;
#pragma unroll
            for (int kh = 0; kh < 7; kh++) {
                int hh = h0 + kh - 3;
                if ((unsigned)hh >= (unsigned)HH) continue;
                const int rb = hh * WWI;
#pragma unroll
                for (int kw = 0; kw < 7; kw++) {
                    int ww = w0 + kw - 3;
                    if ((unsigned)ww >= (unsigned)WWI) continue;
                    acc += ml[rb + ww] * wl[(kh * 7 + kw) * 2]
                         + cl[rb + ww] * wl[(kh * 7 + kw) * 2 + 1];
                }
            }
            ssg[b * LL + pos] = sigmoidf(acc);
        }
    }
}

// -------------------- K5: BN partial stats per (b,slice) ------------------
__global__ void k_bnstat(const float* __restrict__ x, const float* __restrict__ gate,
                         const float* __restrict__ sy, const float* __restrict__ ssg,
                         float* __restrict__ pb) {
    const int b = blockIdx.x, sl = blockIdx.y;
    const int wv = threadIdx.x >> 6, l = threadIdx.x & 63;
    const float4* x4 = (const float4*)x;
    float4 g = ((const float4*)gate)[b * 64 + l];
    float4 s = make_float4(0.f, 0.f, 0.f, 0.f);
    float4 q = make_float4(0.f, 0.f, 0.f, 0.f);
#pragma unroll
    for (int k = 0; k < 8; k++) {
        int pos = b * LL + sl * 32 + k * 4 + wv;
        float4 v = x4[(size_t)pos * 64 + l];
        float g2 = sy[pos] + ssg[pos];
        float fx = v.x * g.x * g2, fy = v.y * g.y * g2, fz = v.z * g.z * g2, fw = v.w * g.w * g2;
        s.x += fx; s.y += fy; s.z += fz; s.w += fw;
        q.x += fx * fx; q.y += fy * fy; q.z += fz * fz; q.w += fw * fw;
    }
    __shared__ float4 ls[4][64], lq[4][64];
    ls[wv][l] = s; lq[wv][l] = q;
    __syncthreads();
    if (wv == 0) {
#pragma unroll
        for (int w = 1; w < 4; w++) {
            float4 a = ls[w][l], c = lq[w][l];
            s.x += a.x; s.y += a.y; s.z += a.z; s.w += a.w;
            q.x += c.x; q.y += c.y; q.z += c.z; q.w += c.w;
        }
        ((float4*)pb)[(b * NSL + sl) * 128 + l] = s;
        ((float4*)pb)[(b * NSL + sl) * 128 + 64 + l] = q;
    }
}

// -------------------- K6: BN reduce + finalize (one block per channel) ----
__global__ void k_bnfin(const float* __restrict__ pb,
                        const float* __restrict__ gamma, const float* __restrict__ beta,
                        float* __restrict__ sc, float* __restrict__ sh) {
    const int c = blockIdx.x;
    const int tid = threadIdx.x;
    float s0 = 0.f, q0 = 0.f;
    for (int sl = tid; sl < BB * NSL; sl += 256) {
        s0 += pb[(size_t)sl * 512 + c];
        q0 += pb[(size_t)sl * 512 + 256 + c];
    }
    __shared__ float rs[256], rq[256];
    rs[tid] = s0; rq[tid] = q0;
    __syncthreads();
    for (int d = 128; d > 0; d >>= 1) {
        if (tid < d) { rs[tid] += rs[tid + d]; rq[tid] += rq[tid + d]; }
        __syncthreads();
    }
    if (tid == 0) {
        const float inv = 1.f / (float)(BB * LL);
        float mean = rs[0] * inv;
        float var  = rq[0] * inv - mean * mean;
        float sv = gamma[c] * rsqrtf(var + EPSV);
        sc[c] = sv;
        sh[c] = beta[c] - mean * sv;
    }
}

// -------------------- K7: normalize + ReLU + write ------------------------
// grid (196, 32): each wave handles 4 positions.
__global__ void k_final(const float* __restrict__ x, const float* __restrict__ gate,
                        const float* __restrict__ sy, const float* __restrict__ ssg,
                        const float* __restrict__ sc, const float* __restrict__ sh,
                        float* __restrict__ out) {
    const int wv = threadIdx.x >> 6, l = threadIdx.x & 63;
    const int b = blockIdx.y;
    const float4 scv = ((const float4*)sc)[l];
    const float4 shv = ((const float4*)sh)[l];
    const float4 g = ((const float4*)gate)[b * 64 + l];
#pragma unroll
    for (int k = 0; k < 4; k++) {
        const int pos = b * LL + blockIdx.x * 16 + k * 4 + wv;
        float4 v = ((const float4*)x)[(size_t)pos * 64 + l];
        float g2 = sy[pos] + ssg[pos];
        float4 o;
        o.x = fmaxf(v.x * g.x * g2 * scv.x + shv.x, 0.f);
        o.y = fmaxf(v.y * g.y * g2 * scv.y + shv.y, 0.f);
        o.z = fmaxf(v.z * g.z * g2 * scv.z + shv.z, 0.f);
        o.w = fmaxf(v.w * g.w * g2 * scv.w + shv.w, 0.f);
        ((float4*)out)[(size_t)pos * 64 + l] = o;
    }
}

extern "C" void kernel_launch(void* const* d_in, const int* in_sizes, int n_in,
                              void* d_out, int out_size, void* d_ws, size_t ws_size,
                              hipStream_t stream) {
    const float* x     = (const float*)d_in[0];
    const float* ca_w1 = (const float*)d_in[1];
    const float* ca_w2 = (const float*)d_in[2];
    const float* lsa_w = (const float*)d_in[3];
    const float* A     = (const float*)d_in[4];
    const float* d_wp  = (const float*)d_in[5];
    const float* d_bp  = (const float*)d_in[6];
    const float* B_wp  = (const float*)d_in[7];
    const float* B_bp  = (const float*)d_in[8];
    const float* C_wp  = (const float*)d_in[9];
    const float* C_bp  = (const float*)d_in[10];
    const float* bn_g  = (const float*)d_in[11];
    const float* bn_b  = (const float*)d_in[12];
    float* out = (float*)d_out;

    // Large partial buffers live in d_out (fully overwritten by k_final).
    float* psum = out;                         // 32*98*256
    float* pmax = psum + BB * NSL * CC;        // 32*98*256
    float* pb   = pmax + BB * NSL * CC;        // 32*98*512  (total 3.2M floats < 25.7M)

    float* ws    = (float*)d_ws;
    float* gate  = ws;                 // 8192
    float* m     = gate  + 8192;       // 100352
    float* cmax  = m     + 100352;     // 100352
    float* sy    = cmax  + 100352;     // 100352
    float* ssg   = sy    + 100352;     // 100352
    float4* mdd  = (float4*)(ssg + 100352);   // 100352 float4s (byte offset 16-aligned)
    float* scv   = (float*)(mdd + 100352);    // 256
    float* shv   = scv   + 256;               // 256

    k_ca_partial<<<dim3(BB, NSL), 256, 0, stream>>>(x, psum, pmax);
    k_ca_fc<<<BB, 256, 0, stream>>>(psum, pmax, ca_w1, ca_w2, gate);
    k_pos_reduce<<<dim3(LL / 16, BB), 256, 0, stream>>>(x, gate, d_wp, d_bp, m, cmax, mdd);
    k_gsa2<<<2 * BB, 896, 0, stream>>>(mdd, m, cmax, B_wp, B_bp, C_wp, C_bp, A, lsa_w, sy, ssg);
    k_bnstat<<<dim3(BB, NSL), 256, 0, stream>>>(x, gate, sy, ssg, pb);
    k_bnfin<<<CC, 256, 0, stream>>>(pb, bn_g, bn_b, scv, shv);
    k_final<<<dim3(LL / 16, BB), 256, 0, stream>>>(x, gate, sy, ssg, scv, shv, out);
}